// Round 1
// baseline (78.983 us; speedup 1.0000x reference)
//
#include <hip/hip_runtime.h>

// Problem constants (from reference): B=4096, N_IN=64, N_OUT=64, M=4096.
#define BATCH 4096
#define NIN   64
#define NOUT  64
#define M_TOT (NIN * NOUT)

// ---------------------------------------------------------------------------
// Kernel 1: build WM from (aW, uW, tW). One thread per m = j*64 + k.
// Store in TRANSPOSED layout for coalesced main-kernel loads:
//   WT[(j*3 + q)*64 + k] = quad q of matrix (j,k), where
//   quad0 = (R00,R01,R02,t0), quad1 = (R10,R11,R12,t1), quad2 = (R20,R21,R22,t2)
// (bottom row [0,0,0,1] is implicit — exploited in the chain kernel)
// Total ws use: 64*3*64 float4 = 12288 float4 = 192 KiB.
// ---------------------------------------------------------------------------
__global__ __launch_bounds__(256) void build_wm_kernel(
    const float* __restrict__ aW, const float* __restrict__ uW,
    const float* __restrict__ tW, float4* __restrict__ WT) {
  int m = blockIdx.x * 256 + threadIdx.x;
  if (m >= M_TOT) return;
  int j = m >> 6, k = m & 63;

  float a  = aW[m];
  float ux = 1.f / (1.f + expf(-uW[3 * m + 0]));
  float uy = 1.f / (1.f + expf(-uW[3 * m + 1]));
  float uz = 1.f / (1.f + expf(-uW[3 * m + 2]));
  float inv = 1.f / sqrtf(ux * ux + uy * uy + uz * uz);
  ux *= inv; uy *= inv; uz *= inv;

  float sa = sinf(a), ca = cosf(a);
  float xx = ux * ux, yy = uy * uy, zz = uz * uz;
  float xy = ux * uy, xz = ux * uz, yz = uy * uz;

  // rot = sin(a)*K + cos(a)*(I3 - uuT) + uuT, K = skew(u)
  float R00 = ca * (1.f - xx) + xx;
  float R01 = -sa * uz + ca * (-xy) + xy;
  float R02 =  sa * uy + ca * (-xz) + xz;
  float R10 =  sa * uz + ca * (-xy) + xy;
  float R11 = ca * (1.f - yy) + yy;
  float R12 = -sa * ux + ca * (-yz) + yz;
  float R20 = -sa * uy + ca * (-xz) + xz;
  float R21 =  sa * ux + ca * (-yz) + yz;
  float R22 = ca * (1.f - zz) + zz;

  float t0 = tW[3 * m + 0], t1 = tW[3 * m + 1], t2 = tW[3 * m + 2];

  WT[(j * 3 + 0) * 64 + k] = make_float4(R00, R01, R02, t0);
  WT[(j * 3 + 1) * 64 + k] = make_float4(R10, R11, R12, t1);
  WT[(j * 3 + 2) * 64 + k] = make_float4(R20, R21, R22, t2);
}

// ---------------------------------------------------------------------------
// Kernel 2: chain product. Thread = one (b,k) pair.
//   wave (64 lanes) = all k for one b  -> I loads are wave-uniform (broadcast)
//   lane k reads WT[(j*3+q)*64 + k]    -> fully coalesced 1 KiB/instr
// carry starts at identity; per j: A = I[b,j] @ W[j,k] (affine-structured),
// carry = carry @ A (full 4x4). Register double-buffering of next-j loads.
// ---------------------------------------------------------------------------
__global__ __launch_bounds__(256) void chain_kernel(
    const float4* __restrict__ I4, const float4* __restrict__ WT,
    float4* __restrict__ O4) {
  const int k = threadIdx.x & 63;
  const int b = blockIdx.x * 4 + (threadIdx.x >> 6);

  const float4* Ib = I4 + (size_t)b * (NIN * 4);  // 4 float4 per j

  float c[16];
#pragma unroll
  for (int i = 0; i < 16; i++) c[i] = (i == 0 || i == 5 || i == 10 || i == 15) ? 1.f : 0.f;

  // prime j=0
  float4 w0 = WT[0 * 64 + k], w1 = WT[1 * 64 + k], w2 = WT[2 * 64 + k];
  float4 i0 = Ib[0], i1 = Ib[1], i2 = Ib[2], i3 = Ib[3];

  for (int j = 0; j < NIN; j++) {
    // prefetch next iteration's operands (dead on last iter; init'd to avoid UB)
    float4 nw0 = w0, nw1 = w1, nw2 = w2;
    float4 ni0 = i0, ni1 = i1, ni2 = i2, ni3 = i3;
    if (j < NIN - 1) {
      const float4* wp = WT + (size_t)(j + 1) * 3 * 64 + k;
      nw0 = wp[0]; nw1 = wp[64]; nw2 = wp[128];
      const float4* ip = Ib + (size_t)(j + 1) * 4;
      ni0 = ip[0]; ni1 = ip[1]; ni2 = ip[2]; ni3 = ip[3];
    }

    // A = I[b,j] @ W  (W bottom row = [0,0,0,1])
    float A[16];
    {
      A[0]  = i0.x * w0.x + i0.y * w1.x + i0.z * w2.x;
      A[1]  = i0.x * w0.y + i0.y * w1.y + i0.z * w2.y;
      A[2]  = i0.x * w0.z + i0.y * w1.z + i0.z * w2.z;
      A[3]  = i0.x * w0.w + i0.y * w1.w + i0.z * w2.w + i0.w;

      A[4]  = i1.x * w0.x + i1.y * w1.x + i1.z * w2.x;
      A[5]  = i1.x * w0.y + i1.y * w1.y + i1.z * w2.y;
      A[6]  = i1.x * w0.z + i1.y * w1.z + i1.z * w2.z;
      A[7]  = i1.x * w0.w + i1.y * w1.w + i1.z * w2.w + i1.w;

      A[8]  = i2.x * w0.x + i2.y * w1.x + i2.z * w2.x;
      A[9]  = i2.x * w0.y + i2.y * w1.y + i2.z * w2.y;
      A[10] = i2.x * w0.z + i2.y * w1.z + i2.z * w2.z;
      A[11] = i2.x * w0.w + i2.y * w1.w + i2.z * w2.w + i2.w;

      A[12] = i3.x * w0.x + i3.y * w1.x + i3.z * w2.x;
      A[13] = i3.x * w0.y + i3.y * w1.y + i3.z * w2.y;
      A[14] = i3.x * w0.z + i3.y * w1.z + i3.z * w2.z;
      A[15] = i3.x * w0.w + i3.y * w1.w + i3.z * w2.w + i3.w;
    }

    // carry = carry @ A
    float n[16];
#pragma unroll
    for (int x = 0; x < 4; x++) {
#pragma unroll
      for (int z = 0; z < 4; z++) {
        n[x * 4 + z] = c[x * 4 + 0] * A[0 * 4 + z] + c[x * 4 + 1] * A[1 * 4 + z] +
                       c[x * 4 + 2] * A[2 * 4 + z] + c[x * 4 + 3] * A[3 * 4 + z];
      }
    }
#pragma unroll
    for (int i = 0; i < 16; i++) c[i] = n[i];

    w0 = nw0; w1 = nw1; w2 = nw2;
    i0 = ni0; i1 = ni1; i2 = ni2; i3 = ni3;
  }

  // store O[b][k] (16 consecutive floats)
  float4* o = O4 + ((size_t)b * NOUT + k) * 4;
  o[0] = make_float4(c[0],  c[1],  c[2],  c[3]);
  o[1] = make_float4(c[4],  c[5],  c[6],  c[7]);
  o[2] = make_float4(c[8],  c[9],  c[10], c[11]);
  o[3] = make_float4(c[12], c[13], c[14], c[15]);
}

extern "C" void kernel_launch(void* const* d_in, const int* in_sizes, int n_in,
                              void* d_out, int out_size, void* d_ws, size_t ws_size,
                              hipStream_t stream) {
  const float* I  = (const float*)d_in[0];
  const float* aW = (const float*)d_in[1];
  const float* uW = (const float*)d_in[2];
  const float* tW = (const float*)d_in[3];

  float4* WT = (float4*)d_ws;  // 192 KiB scratch for transposed WM

  build_wm_kernel<<<M_TOT / 256, 256, 0, stream>>>(aW, uW, tW, WT);
  chain_kernel<<<BATCH / 4, 256, 0, stream>>>((const float4*)I, WT, (float4*)d_out);
}